// Round 7
// baseline (320.382 us; speedup 1.0000x reference)
//
#include <hip/hip_runtime.h>
#include <math.h>

#define NLEVELS 16
#define NDENSE 12   // levels 0-11 dense; 12-15 hashed (structurally stable)
#define NHASH 4
#define TBITS 19
#define TMASK ((1 << TBITS) - 1)
#define BINBITS 6
#define BINS1D (1 << BINBITS)          // 64
#define NBINS (BINS1D * BINS1D)        // 4096 spatial bins (~244 pts each)

typedef float vfloat4 __attribute__((ext_vector_type(4)));

struct Meta {
    float resf[NLEVELS];
    int   resi[NLEVELS];
    int   off[NLEVELS];   // entry offsets (float2 units)
    int   prime;
};

__device__ __forceinline__ int bin_of(float2 u)
{
    int bu = (int)(u.x * (float)BINS1D);   // u,v in [0,1): exact, no clamp needed
    int bv = (int)(u.y * (float)BINS1D);
    // v-major: for fixed v-stripe we sweep u -> hashed xor-windows stream in x
    return bv * BINS1D + bu;
}

// ---- sort prelude -------------------------------------------------------
__global__ __launch_bounds__(256) void zero_kernel(int* __restrict__ hist)
{
    hist[blockIdx.x * 256 + threadIdx.x] = 0;
}

__global__ __launch_bounds__(256) void hist_kernel(
    const float2* __restrict__ uv, int n, int* __restrict__ hist)
{
    __shared__ int lh[NBINS];
    for (int i = threadIdx.x; i < NBINS; i += 256) lh[i] = 0;
    __syncthreads();
    for (int p = blockIdx.x * 256 + threadIdx.x; p < n; p += gridDim.x * 256)
        atomicAdd(&lh[bin_of(uv[p])], 1);
    __syncthreads();
    for (int i = threadIdx.x; i < NBINS; i += 256) {
        int c = lh[i];
        if (c) atomicAdd(&hist[i], c);
    }
}

// 1 block, 256 threads x 16 bins each: exclusive prefix sum in place.
__global__ __launch_bounds__(256) void scan_kernel(int* __restrict__ hist)
{
    __shared__ int part[256];
    int t = threadIdx.x;
    int loc[16];
    int s = 0;
    int base = t * 16;
#pragma unroll
    for (int k = 0; k < 16; ++k) { loc[k] = hist[base + k]; s += loc[k]; }
    part[t] = s;
    __syncthreads();
    for (int d = 1; d < 256; d <<= 1) {
        int v = (t >= d) ? part[t - d] : 0;
        __syncthreads();
        part[t] += v;
        __syncthreads();
    }
    int run = part[t] - s;  // exclusive base for this thread's 16 bins
#pragma unroll
    for (int k = 0; k < 16; ++k) { int c = loc[k]; hist[base + k] = run; run += c; }
}

__global__ __launch_bounds__(256) void scatter_kernel(
    const float2* __restrict__ uv, int n,
    int* __restrict__ offs, int* __restrict__ perm)
{
    int p = blockIdx.x * 256 + threadIdx.x;
    if (p >= n) return;
    int b = bin_of(uv[p]);
    int pos = atomicAdd(&offs[b], 1);   // order nondeterministic; output isn't
    perm[pos] = p;
}

// ---- main kernel: R5 structure + perm indirection -----------------------
__global__ __launch_bounds__(256, 1) void hashgrid2d_kernel(
    const float2* __restrict__ uv,
    const float2* __restrict__ lat,
    const int* __restrict__ perm,     // may be null (fallback: identity)
    float* __restrict__ out,
    Meta m, int n)
{
    int j = blockIdx.x * blockDim.x + threadIdx.x;
    if (j >= n) return;
    int p = perm ? perm[j] : j;

    float2 u = uv[p];
    const float* latf = (const float*)lat;

    float4 da[NDENSE];
    float4 db[NDENSE];
    float2 hv[NHASH][4];

    // Issue all 40 loads up front (max per-wave MLP).
#pragma unroll
    for (int i = 0; i < NDENSE; ++i) {
        float sx = u.x * m.resf[i];
        float sy = u.y * m.resf[i];
        int x0 = (int)floorf(sx);
        int y0 = (int)floorf(sy);
        int base0 = m.off[i] + x0 * m.resi[i] + y0;  // (x0,y0),(x0,y1) adjacent
        int base1 = base0 + m.resi[i];               // (x1,y0),(x1,y1) adjacent
        __builtin_memcpy(&da[i], latf + 2 * (size_t)base0, 16);
        __builtin_memcpy(&db[i], latf + 2 * (size_t)base1, 16);
    }
#pragma unroll
    for (int h = 0; h < NHASH; ++h) {
        int i = NDENSE + h;
        float sx = u.x * m.resf[i];
        float sy = u.y * m.resf[i];
        int x0 = (int)floorf(sx);
        int y0 = (int)floorf(sy);
        int yp0 = y0 * m.prime;
        int yp1 = yp0 + m.prime;
        const float2* tb = lat + m.off[i];
        hv[h][0] = tb[(x0 ^ yp0) & TMASK];
        hv[h][1] = tb[(x0 ^ yp1) & TMASK];
        hv[h][2] = tb[((x0 + 1) ^ yp0) & TMASK];
        hv[h][3] = tb[((x0 + 1) ^ yp1) & TMASK];
    }

    __builtin_amdgcn_sched_barrier(0);

    float o[2 * NLEVELS];
#pragma unroll
    for (int i = 0; i < NDENSE; ++i) {
        float sx = u.x * m.resf[i];
        float sy = u.y * m.resf[i];
        float fx = floorf(sx), fy = floorf(sy);
        float px = sx - fx,   py = sy - fy;
        float w00 = (1.0f - px) * (1.0f - py);
        float w01 = (1.0f - px) * py;
        float w10 = px * (1.0f - py);
        float w11 = px * py;
        o[2*i]   = w00 * da[i].x + w01 * da[i].z + w10 * db[i].x + w11 * db[i].z;
        o[2*i+1] = w00 * da[i].y + w01 * da[i].w + w10 * db[i].y + w11 * db[i].w;
    }
#pragma unroll
    for (int h = 0; h < NHASH; ++h) {
        int i = NDENSE + h;
        float sx = u.x * m.resf[i];
        float sy = u.y * m.resf[i];
        float fx = floorf(sx), fy = floorf(sy);
        float px = sx - fx,   py = sy - fy;
        float w00 = (1.0f - px) * (1.0f - py);
        float w01 = (1.0f - px) * py;
        float w10 = px * (1.0f - py);
        float w11 = px * py;
        o[2*i]   = w00*hv[h][0].x + w01*hv[h][1].x + w10*hv[h][2].x + w11*hv[h][3].x;
        o[2*i+1] = w00*hv[h][0].y + w01*hv[h][1].y + w10*hv[h][2].y + w11*hv[h][3].y;
    }

    // Point p's output row is 128B aligned-contiguous = exactly two full 64B
    // lines -> scattered full-row writes have NO amplification.
    vfloat4* op = (vfloat4*)(out + (size_t)p * (2 * NLEVELS));
#pragma unroll
    for (int jq = 0; jq < 8; ++jq) {
        vfloat4 w;
        w.x = o[4*jq+0]; w.y = o[4*jq+1]; w.z = o[4*jq+2]; w.w = o[4*jq+3];
        op[jq] = w;
    }
}

static void compute_meta(Meta& m)
{
    // EXACTLY mirror the Python reference's double-precision math (same libm):
    const double b = exp((log(2048.0) - log(16.0)) / 15.0);
    int off = 0;
    const long long T = 1LL << TBITS;
    for (int i = 0; i < NLEVELS; ++i) {
        int res = (int)(16.0 * pow(b, (double)i));
        long long n_entries = (long long)(res + 1) * (long long)(res + 1);
        if (n_entries > T) n_entries = T;
        m.resf[i] = (float)res;
        m.resi[i] = res;
        m.off[i]  = off;
        off += (int)n_entries;
    }
    int pr = 1 << 17;
    for (;;) {
        bool isp = true;
        for (long long q = 2; q * q <= pr; ++q)
            if (pr % q == 0) { isp = false; break; }
        if (isp) break;
        ++pr;
    }
    m.prime = pr;
}

extern "C" void kernel_launch(void* const* d_in, const int* in_sizes, int n_in,
                              void* d_out, int out_size, void* d_ws, size_t ws_size,
                              hipStream_t stream)
{
    const float2* uv  = (const float2*)d_in[0];
    const float2* lat = (const float2*)d_in[1];
    float* out = (float*)d_out;

    int n = in_sizes[0] / 2;

    Meta m;
    compute_meta(m);

    const int block = 256;
    const int grid = (n + block - 1) / block;

    size_t ws_needed = (size_t)NBINS * 4 + (size_t)n * 4;
    if (ws_size >= ws_needed) {
        int* hist = (int*)d_ws;                  // NBINS ints
        int* perm = (int*)d_ws + NBINS;          // n ints
        zero_kernel<<<NBINS / 256, 256, 0, stream>>>(hist);
        hist_kernel<<<64, 256, 0, stream>>>(uv, n, hist);
        scan_kernel<<<1, 256, 0, stream>>>(hist);
        scatter_kernel<<<grid, block, 0, stream>>>(uv, n, hist, perm);
        hashgrid2d_kernel<<<grid, block, 0, stream>>>(uv, lat, perm, out, m, n);
    } else {
        hashgrid2d_kernel<<<grid, block, 0, stream>>>(uv, lat, nullptr, out, m, n);
    }
}

// Round 8
// 277.803 us; speedup vs baseline: 1.1533x; 1.1533x over previous
//
#include <hip/hip_runtime.h>
#include <math.h>

#define NLEVELS 16
#define NDENSE 12   // levels 0-11 dense; 12-15 hashed (structurally stable)
#define NHASH 4
#define TBITS 19
#define TMASK ((1 << TBITS) - 1)
#define BINBITS 7
#define BINS1D (1 << BINBITS)          // 128
#define NBINS (BINS1D * BINS1D)        // 16384 bins, ~61 pts each (Poisson)
#define CAP 128                        // slots/bin; P(Pois(61)>128) ~ 8e-13

typedef float vfloat4 __attribute__((ext_vector_type(4)));

struct Meta {
    float resf[NLEVELS];
    int   resi[NLEVELS];
    int   off[NLEVELS];   // entry offsets (float2 units)
    int   prime;
};

__device__ __forceinline__ int bin_of(float2 u)
{
    int bu = (int)(u.x * (float)BINS1D);   // u in [0,1): max 127.99999 -> 127
    int bv = (int)(u.y * (float)BINS1D);
    return bv * BINS1D + bu;
}

// Shared per-point encode body (R7 structure: issue all 40 loads, fence, reduce).
__device__ __forceinline__ void encode_point(
    float2 u, int p,
    const float2* __restrict__ lat,
    float* __restrict__ out,
    const Meta& m)
{
    const float* latf = (const float*)lat;
    float4 da[NDENSE];
    float4 db[NDENSE];
    float2 hv[NHASH][4];

#pragma unroll
    for (int i = 0; i < NDENSE; ++i) {
        float sx = u.x * m.resf[i];
        float sy = u.y * m.resf[i];
        int x0 = (int)floorf(sx);
        int y0 = (int)floorf(sy);
        int base0 = m.off[i] + x0 * m.resi[i] + y0;  // (x0,y0),(x0,y1) adjacent
        int base1 = base0 + m.resi[i];               // (x1,y0),(x1,y1) adjacent
        __builtin_memcpy(&da[i], latf + 2 * (size_t)base0, 16);
        __builtin_memcpy(&db[i], latf + 2 * (size_t)base1, 16);
    }
#pragma unroll
    for (int h = 0; h < NHASH; ++h) {
        int i = NDENSE + h;
        float sx = u.x * m.resf[i];
        float sy = u.y * m.resf[i];
        int x0 = (int)floorf(sx);
        int y0 = (int)floorf(sy);
        int yp0 = y0 * m.prime;
        int yp1 = yp0 + m.prime;
        const float2* tb = lat + m.off[i];
        hv[h][0] = tb[(x0 ^ yp0) & TMASK];
        hv[h][1] = tb[(x0 ^ yp1) & TMASK];
        hv[h][2] = tb[((x0 + 1) ^ yp0) & TMASK];
        hv[h][3] = tb[((x0 + 1) ^ yp1) & TMASK];
    }

    __builtin_amdgcn_sched_barrier(0);

    float o[2 * NLEVELS];
#pragma unroll
    for (int i = 0; i < NDENSE; ++i) {
        float sx = u.x * m.resf[i];
        float sy = u.y * m.resf[i];
        float fx = floorf(sx), fy = floorf(sy);
        float px = sx - fx,   py = sy - fy;
        float w00 = (1.0f - px) * (1.0f - py);
        float w01 = (1.0f - px) * py;
        float w10 = px * (1.0f - py);
        float w11 = px * py;
        o[2*i]   = w00 * da[i].x + w01 * da[i].z + w10 * db[i].x + w11 * db[i].z;
        o[2*i+1] = w00 * da[i].y + w01 * da[i].w + w10 * db[i].y + w11 * db[i].w;
    }
#pragma unroll
    for (int h = 0; h < NHASH; ++h) {
        int i = NDENSE + h;
        float sx = u.x * m.resf[i];
        float sy = u.y * m.resf[i];
        float fx = floorf(sx), fy = floorf(sy);
        float px = sx - fx,   py = sy - fy;
        float w00 = (1.0f - px) * (1.0f - py);
        float w01 = (1.0f - px) * py;
        float w10 = px * (1.0f - py);
        float w11 = px * py;
        o[2*i]   = w00*hv[h][0].x + w01*hv[h][1].x + w10*hv[h][2].x + w11*hv[h][3].x;
        o[2*i+1] = w00*hv[h][0].y + w01*hv[h][1].y + w10*hv[h][2].y + w11*hv[h][3].y;
    }

    // Row p = 128B aligned-contiguous = two full 64B lines: scattered full-row
    // writes have no amplification.
    vfloat4* op = (vfloat4*)(out + (size_t)p * (2 * NLEVELS));
#pragma unroll
    for (int jq = 0; jq < 8; ++jq) {
        vfloat4 w;
        w.x = o[4*jq+0]; w.y = o[4*jq+1]; w.z = o[4*jq+2]; w.w = o[4*jq+3];
        op[jq] = w;
    }
}

// ---- prelude: zero counters, then one-pass capacity-slot binning ----------
__global__ __launch_bounds__(256) void zero_kernel(int* __restrict__ cnt, int total)
{
    int i = blockIdx.x * 256 + threadIdx.x;
    if (i < total) cnt[i] = 0;
}

__global__ __launch_bounds__(256) void scatter_kernel(
    const float2* __restrict__ uv, int n,
    int* __restrict__ cnt, int* __restrict__ ocnt,
    float2* __restrict__ slotUV, int* __restrict__ slotIdx,
    int* __restrict__ overflow)
{
    int p = blockIdx.x * 256 + threadIdx.x;
    if (p >= n) return;
    float2 u = uv[p];
    int b = bin_of(u);
    int s = atomicAdd(&cnt[b], 1);     // slot order nondeterministic; output isn't
    if (s < CAP) {
        slotUV[b * CAP + s]  = u;      // payload: main kernel never gathers uv
        slotIdx[b * CAP + s] = p;
    } else {
        int o = atomicAdd(ocnt, 1);    // overflow sized n -> always in bounds
        overflow[o] = p;
    }
}

// ---- main: one wave = one bin's slot range -> max line merging ------------
__global__ __launch_bounds__(256, 1) void hashgrid2d_main(
    const float2* __restrict__ lat,
    const int* __restrict__ cnt,
    const float2* __restrict__ slotUV,
    const int* __restrict__ slotIdx,
    float* __restrict__ out,
    Meta m)
{
    int b = blockIdx.x * 2 + (threadIdx.x >> 7);   // 2 bins per 256-thread block
    int s = threadIdx.x & (CAP - 1);
    int c = cnt[b];
    if (s >= c) return;                            // fill ~61/128: tail waves exit fast
    float2 u = slotUV[b * CAP + s];
    int p = slotIdx[b * CAP + s];
    encode_point(u, p, lat, out, m);
}

__global__ __launch_bounds__(256) void overflow_kernel(
    const float2* __restrict__ uv,
    const float2* __restrict__ lat,
    const int* __restrict__ ocnt,
    const int* __restrict__ overflow,
    float* __restrict__ out,
    Meta m)
{
    int tot = *ocnt;                               // ~always 0
    for (int j = blockIdx.x * 256 + threadIdx.x; j < tot; j += gridDim.x * 256) {
        int p = overflow[j];
        encode_point(uv[p], p, lat, out, m);
    }
}

// ---- fallback: monolithic (if ws too small) ------------------------------
__global__ __launch_bounds__(256, 1) void hashgrid2d_mono(
    const float2* __restrict__ uv,
    const float2* __restrict__ lat,
    float* __restrict__ out,
    Meta m, int n)
{
    int p = blockIdx.x * blockDim.x + threadIdx.x;
    if (p >= n) return;
    encode_point(uv[p], p, lat, out, m);
}

static void compute_meta(Meta& m)
{
    // EXACTLY mirror the Python reference's double-precision math (same libm):
    const double b = exp((log(2048.0) - log(16.0)) / 15.0);
    int off = 0;
    const long long T = 1LL << TBITS;
    for (int i = 0; i < NLEVELS; ++i) {
        int res = (int)(16.0 * pow(b, (double)i));
        long long n_entries = (long long)(res + 1) * (long long)(res + 1);
        if (n_entries > T) n_entries = T;
        m.resf[i] = (float)res;
        m.resi[i] = res;
        m.off[i]  = off;
        off += (int)n_entries;
    }
    int pr = 1 << 17;
    for (;;) {
        bool isp = true;
        for (long long q = 2; q * q <= pr; ++q)
            if (pr % q == 0) { isp = false; break; }
        if (isp) break;
        ++pr;
    }
    m.prime = pr;
}

extern "C" void kernel_launch(void* const* d_in, const int* in_sizes, int n_in,
                              void* d_out, int out_size, void* d_ws, size_t ws_size,
                              hipStream_t stream)
{
    const float2* uv  = (const float2*)d_in[0];
    const float2* lat = (const float2*)d_in[1];
    float* out = (float*)d_out;

    int n = in_sizes[0] / 2;

    Meta m;
    compute_meta(m);

    // ws layout (bytes):
    //   [0)              cnt: NBINS ints
    //   [NBINS*4)        ocnt: 1 int   (padded to 16640 ints for 8B alignment)
    //   [66560)          slotUV: NBINS*CAP float2  (16 MB)
    //   [+16777216)      slotIdx: NBINS*CAP int    (8 MB)
    //   [+8388608)       overflow: n ints          (4 MB)
    const size_t cnt_ints   = 16640;  // NBINS + 1 + pad
    const size_t uv_bytes   = (size_t)NBINS * CAP * sizeof(float2);
    const size_t idx_bytes  = (size_t)NBINS * CAP * sizeof(int);
    const size_t ws_needed  = cnt_ints * 4 + uv_bytes + idx_bytes + (size_t)n * 4;

    const int block = 256;
    const int grid = (n + block - 1) / block;

    if (ws_size >= ws_needed) {
        int*    cnt      = (int*)d_ws;
        int*    ocnt     = cnt + NBINS;
        float2* slotUV   = (float2*)((char*)d_ws + cnt_ints * 4);
        int*    slotIdx  = (int*)((char*)slotUV + uv_bytes);
        int*    overflow = (int*)((char*)slotIdx + idx_bytes);

        zero_kernel<<<(NBINS + 1 + 255) / 256, 256, 0, stream>>>(cnt, NBINS + 1);
        scatter_kernel<<<grid, block, 0, stream>>>(uv, n, cnt, ocnt,
                                                   slotUV, slotIdx, overflow);
        hashgrid2d_main<<<NBINS / 2, 256, 0, stream>>>(lat, cnt, slotUV,
                                                       slotIdx, out, m);
        overflow_kernel<<<64, 256, 0, stream>>>(uv, lat, ocnt, overflow, out, m);
    } else {
        hashgrid2d_mono<<<grid, block, 0, stream>>>(uv, lat, out, m, n);
    }
}